// Round 7
// baseline (2250.176 us; speedup 1.0000x reference)
//
#include <hip/hip_runtime.h>

#define DCH 32
#define EPSV 1e-5f
#define SLOPE 0.01f
#define SSTRIDE 16       // stats stride in floats (64B/channel slot)
#define BSH 7            // bucket shift: 128 nodes per bucket
#define BSZ 128
#define NBMAX 1024       // max buckets handled by LDS paths (N <= 131072)
#define CHUNK 8192       // edges per block in hist/scatter
#define ZPAD 36          // LDS row pad (floats): float4-aligned, spreads banks
#define KPAD 36
#define LOG2E 1.4426950408889634f

#if defined(__has_builtin)
#  if __has_builtin(__builtin_amdgcn_exp2f)
#    define EXP2F(x) __builtin_amdgcn_exp2f(x)
#  endif
#  if __has_builtin(__builtin_amdgcn_rcpf)
#    define RCPF(x) __builtin_amdgcn_rcpf(x)
#  endif
#endif
#ifndef EXP2F
#  define EXP2F(x) exp2f(x)
#endif
#ifndef RCPF
#  define RCPF(x) (1.0f / (x))
#endif

__device__ __forceinline__ unsigned short f2bf(float x) {
    unsigned u = __float_as_uint(x);
    unsigned r = (u + 0x7FFFu + ((u >> 16) & 1u)) >> 16;   // RNE
    return (unsigned short)r;
}

// ---------------- bucket histogram (LDS-staged) ----------------
__global__ __launch_bounds__(256) void k_bucket_hist(const int* __restrict__ dst,
                                                     int* __restrict__ bcnt, int E, int NB) {
    __shared__ int h[NBMAX];
    const int t = threadIdx.x;
    const int e0 = blockIdx.x * CHUNK;
    const int e1 = min(e0 + CHUNK, E);
    if (NB <= NBMAX) {
        for (int j = t; j < NB; j += 256) h[j] = 0;
        __syncthreads();
        for (int e = e0 + t; e < e1; e += 256) atomicAdd(&h[dst[e] >> BSH], 1);
        __syncthreads();
        for (int j = t; j < NB; j += 256) if (h[j]) atomicAdd(&bcnt[j], h[j]);
    } else {
        for (int e = e0 + t; e < e1; e += 256) atomicAdd(&bcnt[dst[e] >> BSH], 1);
    }
}

// ---------------- single-block chunked exclusive scan ----------------
__global__ __launch_bounds__(1024) void k_scan(const int* __restrict__ deg, int* __restrict__ off, int N) {
    __shared__ int wsum[16];
    __shared__ int woff[16];
    __shared__ int ctot;
    __shared__ int carry;
    const int t = threadIdx.x;
    const int lane = t & 63;
    const int w = t >> 6;
    if (t == 0) carry = 0;
    __syncthreads();
    for (int base = 0; base < N; base += 1024) {
        const int i = base + t;
        const int v = (i < N) ? deg[i] : 0;
        int incl = v;
        #pragma unroll
        for (int d = 1; d < 64; d <<= 1) {
            int tmp = __shfl_up(incl, d);
            if (lane >= d) incl += tmp;
        }
        if (lane == 63) wsum[w] = incl;
        __syncthreads();
        if (t < 16) {
            const int a = wsum[t];
            int in = a;
            #pragma unroll
            for (int d = 1; d < 16; d <<= 1) {
                int tmp = __shfl_up(in, d);
                if (t >= d) in += tmp;
            }
            woff[t] = in - a;
            if (t == 15) ctot = in;
        }
        __syncthreads();
        if (i < N) off[i] = carry + woff[w] + incl - v;
        __syncthreads();
        if (t == 0) carry += ctot;
        __syncthreads();
    }
    if (t == 0) off[N] = carry;
}

// ---------------- bucket scatter: packed (src<<7)|dst_local into bucket-grouped runs ----------------
__global__ __launch_bounds__(256) void k_bucket_scatter(const int* __restrict__ src, const int* __restrict__ dst,
                                                        const int* __restrict__ boff, int* __restrict__ cur,
                                                        unsigned int* __restrict__ pairs, int E, int NB) {
    const int t = threadIdx.x;
    const int e0 = blockIdx.x * CHUNK;
    const int e1 = min(e0 + CHUNK, E);
    if (NB <= NBMAX) {
        __shared__ int cnt[NBMAX];
        __shared__ int base[NBMAX];
        for (int j = t; j < NB; j += 256) { cnt[j] = 0; }
        __syncthreads();
        for (int e = e0 + t; e < e1; e += 256) atomicAdd(&cnt[dst[e] >> BSH], 1);
        __syncthreads();
        for (int j = t; j < NB; j += 256) {
            const int c = cnt[j];
            if (c) base[j] = atomicAdd(&cur[j], c);
            cnt[j] = 0;          // reuse as rank counter
        }
        __syncthreads();
        for (int e = e0 + t; e < e1; e += 256) {
            const int d = dst[e];
            const int bk = d >> BSH;
            const int r = atomicAdd(&cnt[bk], 1);
            pairs[boff[bk] + base[bk] + r] = ((unsigned)src[e] << BSH) | (unsigned)(d & (BSZ - 1));
        }
    } else {
        for (int e = e0 + t; e < e1; e += 256) {
            const int d = dst[e];
            const int bk = d >> BSH;
            const int r = atomicAdd(&cur[bk], 1);
            pairs[boff[bk] + r] = ((unsigned)src[e] << BSH) | (unsigned)(d & (BSZ - 1));
        }
    }
}

// ---------------- fused: [BN of prev layer] + 4-way projection ----------------
__global__ __launch_bounds__(256) void k_project(
    const float* __restrict__ xin,
    const float* __restrict__ statsPrev, const float* __restrict__ gPrev, const float* __restrict__ bPrev,
    const float* __restrict__ Wk, const float* __restrict__ bk,
    const float* __restrict__ Wq, const float* __restrict__ bq,
    const float* __restrict__ Wv, const float* __restrict__ bv,
    const float* __restrict__ Ws, const float* __restrict__ bs,
    float* __restrict__ kout, uint4* __restrict__ qvout,
    float* __restrict__ zout, float* __restrict__ statsCur,
    int N, int do_bn, float invN)
{
    __shared__ float wk[DCH][DCH + 1], wq[DCH][DCH + 1], wv[DCH][DCH + 1], wsk[DCH][DCH + 1];
    __shared__ float xs[8][DCH];
    __shared__ unsigned short qvs[8][64];
    const int t = threadIdx.x;
    if (blockIdx.x == 0) {
        for (int i = t; i < 2048; i += 256) statsCur[i] = 0.f;
    }
    for (int i = t; i < DCH * DCH; i += 256) {
        const int c = i >> 5, d = i & 31;
        wk[c][d] = Wk[i];
        wq[c][d] = Wq[i];
        wv[c][d] = Wv[i];
        wsk[c][d] = Ws[i];
    }
    const int li = t >> 5;
    const int c  = t & 31;
    const int node = blockIdx.x * 8 + li;
    if (node < N) {
        float xv = xin[node * DCH + c];
        if (do_bn) {
            const float mn = statsPrev[c * SSTRIDE] * invN;
            const float var = statsPrev[1024 + c * SSTRIDE] * invN - mn * mn;
            const float sc = rsqrtf(var + EPSV) * gPrev[c];
            xv = (xv - mn) * sc + bPrev[c];
        }
        xs[li][c] = xv;
    }
    __syncthreads();
    if (node < N) {
        float aK = 0.f, aQ = 0.f, aV = 0.f, aS = 0.f;
        #pragma unroll
        for (int d = 0; d < DCH; ++d) {
            const float xv = xs[li][d];
            aK += xv * wk[c][d];
            aQ += xv * wq[c][d];
            aV += xv * wv[c][d];
            aS += xv * wsk[c][d];
        }
        const int o = node * DCH + c;
        kout[o] = -LOG2E * (aK + bk[c]);
        zout[o] = aS + bs[c];
        const int g = c >> 2, j = c & 3;
        qvs[li][g * 8 + j]     = f2bf(-LOG2E * (aQ + bq[c]));
        qvs[li][g * 8 + 4 + j] = f2bf(aV + bv[c]);
    }
    __syncthreads();
    if (t < 64) {
        const int ln = t >> 3, g = t & 7;
        const int nd = blockIdx.x * 8 + ln;
        if (nd < N) qvout[nd * 8 + g] = ((const uint4*)qvs[ln])[g];
    }
}

// per-edge processing: decode bf16 q|v, gate with LDS-staged kn, ds_add into LDS z
#define EDGE_PROC(u, a)                                                      \
    do {                                                                     \
        const int dl = (int)((u) & (BSZ - 1));                               \
        const float4 kk = *(const float4*)&ks[dl * KPAD + p4];               \
        const float q0 = __uint_as_float((a).x << 16);                       \
        const float q1 = __uint_as_float((a).x & 0xffff0000u);               \
        const float q2 = __uint_as_float((a).y << 16);                       \
        const float q3 = __uint_as_float((a).y & 0xffff0000u);               \
        const float v0 = __uint_as_float((a).z << 16);                       \
        const float v1 = __uint_as_float((a).z & 0xffff0000u);               \
        const float v2 = __uint_as_float((a).w << 16);                       \
        const float v3 = __uint_as_float((a).w & 0xffff0000u);               \
        float* zp = &zs[dl * ZPAD + p4];                                     \
        atomicAdd(zp + 0, v0 * RCPF(1.f + EXP2F(kk.x + q0)));                \
        atomicAdd(zp + 1, v1 * RCPF(1.f + EXP2F(kk.y + q1)));                \
        atomicAdd(zp + 2, v2 * RCPF(1.f + EXP2F(kk.z + q2)));                \
        atomicAdd(zp + 3, v3 * RCPF(1.f + EXP2F(kk.w + q3)));                \
    } while (0)

// ---------------- bucket-parallel edge kernel: one 128-node dst bucket per block ----------------
// Edge-parallel (8 lanes/edge, 32 edges/step, unroll x4). z accumulates in LDS.
// Epilogue fuses skip + leaky + BN(prev) residual + stats + z write.
__global__ __launch_bounds__(256) void k_edges_bucket(
    const unsigned int* __restrict__ pairs, const int* __restrict__ boff,
    const float* __restrict__ kn,            // [N][32] f32 = -log2e*k
    const uint4* __restrict__ qv4,           // [N][8] packed bf16 {qn,v}
    const float4* __restrict__ zprev4,       // prev layer pre-BN z (or x)
    const float* __restrict__ statsPrev, const float* __restrict__ gPrev, const float* __restrict__ bPrev,
    float4* __restrict__ z4,                 // in: skip init; out: z
    float* __restrict__ statsCur, int N, int do_leaky, int do_bn, float invN)
{
    __shared__ float zs[BSZ * ZPAD];
    __shared__ float ks[BSZ * KPAD];
    __shared__ float sm[4][DCH], sq[4][DCH];
    const int t = threadIdx.x;
    const int b = blockIdx.x;
    const int node0 = b << BSH;
    const int nvalid = min(BSZ, N - node0);

    for (int i = t; i < BSZ * ZPAD; i += 256) zs[i] = 0.f;
    for (int i = t; i < nvalid * DCH; i += 256)
        ks[(i >> 5) * KPAD + (i & 31)] = kn[(size_t)node0 * DCH + i];
    __syncthreads();

    const int p = t & 7;
    const int p4 = p * 4;
    const int g = t >> 3;                    // edge slot 0..31
    const int begin = boff[b], end = boff[b + 1];

    int e = begin + g;
    for (; e + 96 < end; e += 128) {
        const unsigned u0 = pairs[e];
        const unsigned u1 = pairs[e + 32];
        const unsigned u2 = pairs[e + 64];
        const unsigned u3 = pairs[e + 96];
        const uint4 a0 = qv4[(size_t)(u0 >> BSH) * 8 + p];
        const uint4 a1 = qv4[(size_t)(u1 >> BSH) * 8 + p];
        const uint4 a2 = qv4[(size_t)(u2 >> BSH) * 8 + p];
        const uint4 a3 = qv4[(size_t)(u3 >> BSH) * 8 + p];
        EDGE_PROC(u0, a0);
        EDGE_PROC(u1, a1);
        EDGE_PROC(u2, a2);
        EDGE_PROC(u3, a3);
    }
    for (; e < end; e += 32) {
        const unsigned u = pairs[e];
        const uint4 a = qv4[(size_t)(u >> BSH) * 8 + p];
        EDGE_PROC(u, a);
    }
    __syncthreads();

    // epilogue: skip + leaky + BN(prev) residual + stats + write
    float scv[4] = {1.f, 1.f, 1.f, 1.f}, shv[4] = {0.f, 0.f, 0.f, 0.f};
    if (do_bn) {
        #pragma unroll
        for (int j = 0; j < 4; ++j) {
            const int c = p4 + j;
            const float mn = statsPrev[c * SSTRIDE] * invN;
            const float var = statsPrev[1024 + c * SSTRIDE] * invN - mn * mn;
            const float rs = rsqrtf(var + EPSV) * gPrev[c];
            scv[j] = rs;
            shv[j] = bPrev[c] - mn * rs;
        }
    }
    float s0 = 0.f, s1 = 0.f, s2 = 0.f, s3 = 0.f;
    float r0 = 0.f, r1 = 0.f, r2 = 0.f, r3 = 0.f;
    for (int m = t; m < nvalid * 8; m += 256) {
        const int n = m >> 3;                // (m&7)==p since 256%8==0
        float4 z = *(const float4*)&zs[n * ZPAD + p4];
        const size_t gi = (size_t)node0 * 8 + m;
        const float4 zi = z4[gi];            // skip init from k_project
        z.x += zi.x; z.y += zi.y; z.z += zi.z; z.w += zi.w;
        if (do_leaky) {
            z.x = z.x >= 0.f ? z.x : SLOPE * z.x;
            z.y = z.y >= 0.f ? z.y : SLOPE * z.y;
            z.z = z.z >= 0.f ? z.z : SLOPE * z.z;
            z.w = z.w >= 0.f ? z.w : SLOPE * z.w;
        }
        const float4 hz = zprev4[gi];
        z.x += hz.x * scv[0] + shv[0];
        z.y += hz.y * scv[1] + shv[1];
        z.z += hz.z * scv[2] + shv[2];
        z.w += hz.w * scv[3] + shv[3];
        z4[gi] = z;
        s0 += z.x; s1 += z.y; s2 += z.z; s3 += z.w;
        r0 += z.x * z.x; r1 += z.y * z.y; r2 += z.z * z.z; r3 += z.w * z.w;
    }
    const int lane = t & 63;
    const int w = t >> 6;
    #pragma unroll
    for (int d = 8; d < 64; d <<= 1) {
        s0 += __shfl_down(s0, d); s1 += __shfl_down(s1, d);
        s2 += __shfl_down(s2, d); s3 += __shfl_down(s3, d);
        r0 += __shfl_down(r0, d); r1 += __shfl_down(r1, d);
        r2 += __shfl_down(r2, d); r3 += __shfl_down(r3, d);
    }
    if (lane < 8) {
        sm[w][p4 + 0] = s0; sm[w][p4 + 1] = s1; sm[w][p4 + 2] = s2; sm[w][p4 + 3] = s3;
        sq[w][p4 + 0] = r0; sq[w][p4 + 1] = r1; sq[w][p4 + 2] = r2; sq[w][p4 + 3] = r3;
    }
    __syncthreads();
    if (t < DCH) {
        const float a = sm[0][t] + sm[1][t] + sm[2][t] + sm[3][t];
        const float bb = sq[0][t] + sq[1][t] + sq[2][t] + sq[3][t];
        atomicAdd(&statsCur[t * SSTRIDE], a);
        atomicAdd(&statsCur[1024 + t * SSTRIDE], bb);
    }
}

// ---------------- final batchnorm apply ----------------
__global__ __launch_bounds__(256) void k_bn(
    const float* __restrict__ z, const float* __restrict__ stats,
    const float* __restrict__ gamma, const float* __restrict__ beta,
    float* __restrict__ out, int total, float invN)
{
    const int i = blockIdx.x * 256 + threadIdx.x;
    if (i >= total) return;
    const int c = i & 31;
    const float mean = stats[c * SSTRIDE] * invN;
    const float var  = stats[1024 + c * SSTRIDE] * invN - mean * mean;
    out[i] = (z[i] - mean) * rsqrtf(var + EPSV) * gamma[c] + beta[c];
}

extern "C" void kernel_launch(void* const* d_in, const int* in_sizes, int n_in,
                              void* d_out, int out_size, void* d_ws, size_t ws_size,
                              hipStream_t stream) {
    const float* x     = (const float*)d_in[0];
    const int*   ei    = (const int*)  d_in[1];
    const float* Wk    = (const float*)d_in[3];
    const float* bk    = (const float*)d_in[4];
    const float* Wq    = (const float*)d_in[5];
    const float* bq    = (const float*)d_in[6];
    const float* Wv    = (const float*)d_in[7];
    const float* bv    = (const float*)d_in[8];
    const float* Ws    = (const float*)d_in[9];
    const float* bs    = (const float*)d_in[10];
    const float* gamma = (const float*)d_in[11];
    const float* beta  = (const float*)d_in[12];

    const int N = in_sizes[0] / DCH;
    const int E = in_sizes[1] / 2;
    const int NB = (N + BSZ - 1) >> BSH;
    const int* src = ei;
    const int* dst = ei + E;

    float* ws     = (float*)d_ws;
    float* kbuf   = ws;                                   // N*32 f32 (pre-scaled -log2e*k)
    unsigned short* qvbuf = (unsigned short*)(kbuf + (size_t)N * DCH);   // N*64 u16
    float* zA     = (float*)qvbuf + (size_t)N * DCH;      // N*32 f32
    float* zB     = zA + (size_t)N * DCH;
    float* statsA = zB + (size_t)N * DCH;                 // 2048
    float* statsB = statsA + 2048;                        // 2048
    int*   bcnt   = (int*)(statsB + 2048);                // NB
    int*   boff   = bcnt + NB;                            // NB+1
    int*   cur    = boff + NB + 1;                        // NB
    unsigned int* pairs = (unsigned int*)(cur + NB);      // E

    const int total = N * DCH;
    const float invN = 1.f / (float)N;

    // ---- build bucketed edge list once per launch ----
    hipMemsetAsync(bcnt, 0, (size_t)NB * sizeof(int), stream);
    hipMemsetAsync(cur, 0, (size_t)NB * sizeof(int), stream);
    const int nchunk = (E + CHUNK - 1) / CHUNK;
    k_bucket_hist<<<nchunk, 256, 0, stream>>>(dst, bcnt, E, NB);
    k_scan<<<1, 1024, 0, stream>>>(bcnt, boff, NB);
    k_bucket_scatter<<<nchunk, 256, 0, stream>>>(src, dst, boff, cur, pairs, E, NB);

    const float* zprev = x;
    const float* statsPrev = nullptr;
    for (int l = 0; l < 3; ++l) {
        const size_t wo = (size_t)l * DCH * DCH;
        const size_t bo = (size_t)l * DCH;
        float* zcur = (l & 1) ? zB : zA;
        float* statsCur = (l & 1) ? statsB : statsA;
        const float* gPrev = (l > 0) ? gamma + (size_t)(l - 1) * DCH : gamma;
        const float* bPrev = (l > 0) ? beta + (size_t)(l - 1) * DCH : beta;
        const int do_bn = (l > 0) ? 1 : 0;
        const float* sPrev = do_bn ? statsPrev : statsA;

        k_project<<<(N + 7) / 8, 256, 0, stream>>>(
            zprev, sPrev, gPrev, bPrev,
            Wk + wo, bk + bo, Wq + wo, bq + bo, Wv + wo, bv + bo, Ws + wo, bs + bo,
            kbuf, (uint4*)qvbuf, zcur, statsCur, N, do_bn, invN);
        k_edges_bucket<<<NB, 256, 0, stream>>>(
            pairs, boff, kbuf, (const uint4*)qvbuf,
            (const float4*)zprev, sPrev, gPrev, bPrev,
            (float4*)zcur, statsCur, N, (l < 2) ? 1 : 0, do_bn, invN);

        statsPrev = statsCur;
        zprev = zcur;
    }
    k_bn<<<(total + 255) / 256, 256, 0, stream>>>(
        zA, statsA, gamma + 2 * DCH, beta + 2 * DCH, (float*)d_out, total, invN);
}

// Round 8
// 1173.063 us; speedup vs baseline: 1.9182x; 1.9182x over previous
//
#include <hip/hip_runtime.h>

#define DCH 32
#define EPSV 1e-5f
#define SLOPE 0.01f
#define SSTRIDE 16       // stats stride in floats (64B/channel slot)
#define BSH 7            // bucket shift: 128 nodes per bucket
#define BSZ 128
#define NBMAX 1024       // max buckets handled by LDS paths (N <= 131072)
#define CHUNK 8192       // edges per block in hist/scatter
#define CAP 6144         // max edges per bucket for LDS-staged CSR build
#define LOG2E 1.4426950408889634f

#if defined(__has_builtin)
#  if __has_builtin(__builtin_amdgcn_exp2f)
#    define EXP2F(x) __builtin_amdgcn_exp2f(x)
#  endif
#  if __has_builtin(__builtin_amdgcn_rcpf)
#    define RCPF(x) __builtin_amdgcn_rcpf(x)
#  endif
#endif
#ifndef EXP2F
#  define EXP2F(x) exp2f(x)
#endif
#ifndef RCPF
#  define RCPF(x) (1.0f / (x))
#endif

__device__ __forceinline__ unsigned short f2bf(float x) {
    unsigned u = __float_as_uint(x);
    unsigned r = (u + 0x7FFFu + ((u >> 16) & 1u)) >> 16;   // RNE
    return (unsigned short)r;
}

// ---------------- bucket histogram (LDS-staged) ----------------
__global__ __launch_bounds__(256) void k_bucket_hist(const int* __restrict__ dst,
                                                     int* __restrict__ bcnt, int E, int NB) {
    __shared__ int h[NBMAX];
    const int t = threadIdx.x;
    const int e0 = blockIdx.x * CHUNK;
    const int e1 = min(e0 + CHUNK, E);
    if (NB <= NBMAX) {
        for (int j = t; j < NB; j += 256) h[j] = 0;
        __syncthreads();
        for (int e = e0 + t; e < e1; e += 256) atomicAdd(&h[dst[e] >> BSH], 1);
        __syncthreads();
        for (int j = t; j < NB; j += 256) if (h[j]) atomicAdd(&bcnt[j], h[j]);
    } else {
        for (int e = e0 + t; e < e1; e += 256) atomicAdd(&bcnt[dst[e] >> BSH], 1);
    }
}

// ---------------- single-block chunked exclusive scan ----------------
__global__ __launch_bounds__(1024) void k_scan(const int* __restrict__ deg, int* __restrict__ off, int N) {
    __shared__ int wsum[16];
    __shared__ int woff[16];
    __shared__ int ctot;
    __shared__ int carry;
    const int t = threadIdx.x;
    const int lane = t & 63;
    const int w = t >> 6;
    if (t == 0) carry = 0;
    __syncthreads();
    for (int base = 0; base < N; base += 1024) {
        const int i = base + t;
        const int v = (i < N) ? deg[i] : 0;
        int incl = v;
        #pragma unroll
        for (int d = 1; d < 64; d <<= 1) {
            int tmp = __shfl_up(incl, d);
            if (lane >= d) incl += tmp;
        }
        if (lane == 63) wsum[w] = incl;
        __syncthreads();
        if (t < 16) {
            const int a = wsum[t];
            int in = a;
            #pragma unroll
            for (int d = 1; d < 16; d <<= 1) {
                int tmp = __shfl_up(in, d);
                if (t >= d) in += tmp;
            }
            woff[t] = in - a;
            if (t == 15) ctot = in;
        }
        __syncthreads();
        if (i < N) off[i] = carry + woff[w] + incl - v;
        __syncthreads();
        if (t == 0) carry += ctot;
        __syncthreads();
    }
    if (t == 0) off[N] = carry;
}

// ---------------- bucket scatter: packed (src<<7)|dst_local into bucket-grouped runs ----------------
__global__ __launch_bounds__(256) void k_bucket_scatter(const int* __restrict__ src, const int* __restrict__ dst,
                                                        const int* __restrict__ boff, int* __restrict__ cur,
                                                        unsigned int* __restrict__ pairs, int E, int NB) {
    const int t = threadIdx.x;
    const int e0 = blockIdx.x * CHUNK;
    const int e1 = min(e0 + CHUNK, E);
    if (NB <= NBMAX) {
        __shared__ int cnt[NBMAX];
        __shared__ int base[NBMAX];
        for (int j = t; j < NB; j += 256) { cnt[j] = 0; }
        __syncthreads();
        for (int e = e0 + t; e < e1; e += 256) atomicAdd(&cnt[dst[e] >> BSH], 1);
        __syncthreads();
        for (int j = t; j < NB; j += 256) {
            const int c = cnt[j];
            if (c) base[j] = atomicAdd(&cur[j], c);
            cnt[j] = 0;          // reuse as rank counter
        }
        __syncthreads();
        for (int e = e0 + t; e < e1; e += 256) {
            const int d = dst[e];
            const int bk = d >> BSH;
            const int r = atomicAdd(&cnt[bk], 1);
            pairs[boff[bk] + base[bk] + r] = ((unsigned)src[e] << BSH) | (unsigned)(d & (BSZ - 1));
        }
    } else {
        for (int e = e0 + t; e < e1; e += 256) {
            const int d = dst[e];
            const int bk = d >> BSH;
            const int r = atomicAdd(&cur[bk], 1);
            pairs[boff[bk] + r] = ((unsigned)src[e] << BSH) | (unsigned)(d & (BSZ - 1));
        }
    }
}

// ---------------- per-bucket CSR build: node histogram + scan + dense ssrc ----------------
__global__ __launch_bounds__(256) void k_build_csr(const unsigned int* __restrict__ pairs,
                                                   const int* __restrict__ boff,
                                                   int* __restrict__ deg, int* __restrict__ off,
                                                   int* __restrict__ ssrc, int N) {
    __shared__ int cnt[BSZ];
    __shared__ int scn[BSZ];
    __shared__ int rnk[BSZ];
    __shared__ int stage[CAP];
    const int t = threadIdx.x;
    const int b = blockIdx.x;
    const int begin = boff[b], end = boff[b + 1];
    const int total = end - begin;
    if (t < BSZ) { cnt[t] = 0; rnk[t] = 0; }
    __syncthreads();
    for (int i = begin + t; i < end; i += 256) atomicAdd(&cnt[pairs[i] & (BSZ - 1)], 1);
    __syncthreads();
    if (t < BSZ) scn[t] = cnt[t];
    __syncthreads();
    #pragma unroll
    for (int s = 1; s < BSZ; s <<= 1) {
        int add = 0;
        if (t < BSZ && t >= s) add = scn[t - s];
        __syncthreads();
        if (t < BSZ) scn[t] += add;
        __syncthreads();
    }
    const int node0 = b << BSH;
    if (t < BSZ && node0 + t < N) {
        deg[node0 + t] = cnt[t];
        off[node0 + t] = begin + scn[t] - cnt[t];
    }
    if (total <= CAP) {
        for (int i = begin + t; i < end; i += 256) {
            const unsigned u = pairs[i];
            const int nl = u & (BSZ - 1);
            const int r = atomicAdd(&rnk[nl], 1);
            stage[scn[nl] - cnt[nl] + r] = (int)(u >> BSH);
        }
        __syncthreads();
        for (int i = t; i < total; i += 256) ssrc[begin + i] = stage[i];
    } else {
        for (int i = begin + t; i < end; i += 256) {
            const unsigned u = pairs[i];
            const int nl = u & (BSZ - 1);
            const int r = atomicAdd(&rnk[nl], 1);
            ssrc[begin + scn[nl] - cnt[nl] + r] = (int)(u >> BSH);
        }
    }
}

// ---------------- fused: [BN of prev layer] + 4-way projection ----------------
__global__ __launch_bounds__(256) void k_project(
    const float* __restrict__ xin,
    const float* __restrict__ statsPrev, const float* __restrict__ gPrev, const float* __restrict__ bPrev,
    const float* __restrict__ Wk, const float* __restrict__ bk,
    const float* __restrict__ Wq, const float* __restrict__ bq,
    const float* __restrict__ Wv, const float* __restrict__ bv,
    const float* __restrict__ Ws, const float* __restrict__ bs,
    float* __restrict__ kout, uint4* __restrict__ qvout,
    float* __restrict__ zout, float* __restrict__ statsCur,
    int N, int do_bn, float invN)
{
    __shared__ float wk[DCH][DCH + 1], wq[DCH][DCH + 1], wv[DCH][DCH + 1], wsk[DCH][DCH + 1];
    __shared__ float xs[8][DCH];
    __shared__ unsigned short qvs[8][64];
    const int t = threadIdx.x;
    if (blockIdx.x == 0) {
        for (int i = t; i < 2048; i += 256) statsCur[i] = 0.f;
    }
    for (int i = t; i < DCH * DCH; i += 256) {
        const int c = i >> 5, d = i & 31;
        wk[c][d] = Wk[i];
        wq[c][d] = Wq[i];
        wv[c][d] = Wv[i];
        wsk[c][d] = Ws[i];
    }
    const int li = t >> 5;
    const int c  = t & 31;
    const int node = blockIdx.x * 8 + li;
    if (node < N) {
        float xv = xin[node * DCH + c];
        if (do_bn) {
            const float mn = statsPrev[c * SSTRIDE] * invN;
            const float var = statsPrev[1024 + c * SSTRIDE] * invN - mn * mn;
            const float sc = rsqrtf(var + EPSV) * gPrev[c];
            xv = (xv - mn) * sc + bPrev[c];
        }
        xs[li][c] = xv;
    }
    __syncthreads();
    if (node < N) {
        float aK = 0.f, aQ = 0.f, aV = 0.f, aS = 0.f;
        #pragma unroll
        for (int d = 0; d < DCH; ++d) {
            const float xv = xs[li][d];
            aK += xv * wk[c][d];
            aQ += xv * wq[c][d];
            aV += xv * wv[c][d];
            aS += xv * wsk[c][d];
        }
        const int o = node * DCH + c;
        kout[o] = -LOG2E * (aK + bk[c]);
        zout[o] = aS + bs[c];
        const int g = c >> 2, j = c & 3;
        qvs[li][g * 8 + j]     = f2bf(-LOG2E * (aQ + bq[c]));
        qvs[li][g * 8 + 4 + j] = f2bf(aV + bv[c]);
    }
    __syncthreads();
    if (t < 64) {
        const int ln = t >> 3, g = t & 7;
        const int nd = blockIdx.x * 8 + ln;
        if (nd < N) qvout[nd * 8 + g] = ((const uint4*)qvs[ln])[g];
    }
}

// gate accumulate helper: acc += v * sigmoid (exp2 form, kn/qn pre-scaled by -log2e)
#define GATE_ACC(u, ax, ay, az, aw)                                          \
    do {                                                                     \
        const float q0 = __uint_as_float((u).x << 16);                       \
        const float q1 = __uint_as_float((u).x & 0xffff0000u);               \
        const float q2 = __uint_as_float((u).y << 16);                       \
        const float q3 = __uint_as_float((u).y & 0xffff0000u);               \
        const float v0 = __uint_as_float((u).z << 16);                       \
        const float v1 = __uint_as_float((u).z & 0xffff0000u);               \
        const float v2 = __uint_as_float((u).w << 16);                       \
        const float v3 = __uint_as_float((u).w & 0xffff0000u);               \
        ax = fmaf(v0, RCPF(1.f + EXP2F(kn.x + q0)), ax);                     \
        ay = fmaf(v1, RCPF(1.f + EXP2F(kn.y + q1)), ay);                     \
        az = fmaf(v2, RCPF(1.f + EXP2F(kn.z + q2)), az);                     \
        aw = fmaf(v3, RCPF(1.f + EXP2F(kn.w + q3)), aw);                     \
    } while (0)

// ---------------- dst-centric gather, 4 groups per node ----------------
// 8 nodes/block. Group g (of 32) serves node g>>2, edge sublist (g&3)::4.
// Per node: 16 independent gathers in flight, serial chain ~deg/4.
// Partials combine via shfl_down(8,16); sub==0 lanes run the epilogue.
__global__ __launch_bounds__(256) void k_edges_csr(
    const int* __restrict__ off, const int* __restrict__ deg, const int* __restrict__ ssrc,
    const float4* __restrict__ kn4, const uint4* __restrict__ qv4,
    const float4* __restrict__ zprev4,
    const float* __restrict__ statsPrev, const float* __restrict__ gPrev, const float* __restrict__ bPrev,
    float4* __restrict__ z4,
    float* __restrict__ statsCur, int N, int do_leaky, int do_bn, float invN)
{
    const int t = threadIdx.x;
    const int p = t & 7;
    const int g = t >> 3;        // 0..31
    const int sub = g & 3;       // quarter of the edge list
    const int n = blockIdx.x * 8 + (g >> 2);
    const int lane = t & 63;
    const int w = t >> 6;

    float ax = 0.f, ay = 0.f, az = 0.f, aw = 0.f;
    int idx = 0;
    if (n < N) {
        idx = n * 8 + p;
        const float4 kn = kn4[idx];
        float bx = 0.f, by = 0.f, bz = 0.f, bw = 0.f;
        const int beg = off[n];
        const int end = beg + deg[n];
        int e = beg + sub;
        // unroll x4 at stride 4: 4 independent gathers in flight per lane
        for (; e + 12 < end; e += 16) {
            const int sA = ssrc[e];
            const int sB = ssrc[e + 4];
            const int sC = ssrc[e + 8];
            const int sD = ssrc[e + 12];
            const uint4 uA = qv4[(size_t)sA * 8 + p];
            const uint4 uB = qv4[(size_t)sB * 8 + p];
            const uint4 uC = qv4[(size_t)sC * 8 + p];
            const uint4 uD = qv4[(size_t)sD * 8 + p];
            GATE_ACC(uA, ax, ay, az, aw);
            GATE_ACC(uB, bx, by, bz, bw);
            GATE_ACC(uC, ax, ay, az, aw);
            GATE_ACC(uD, bx, by, bz, bw);
        }
        for (; e < end; e += 4) {
            const int s = ssrc[e];
            const uint4 u = qv4[(size_t)s * 8 + p];
            GATE_ACC(u, ax, ay, az, aw);
        }
        ax += bx; ay += by; az += bz; aw += bw;
    }
    // combine the 4 subgroup partials into sub==0 lanes (t, t+8, t+16, t+24)
    ax += __shfl_down(ax, 8);  ay += __shfl_down(ay, 8);
    az += __shfl_down(az, 8);  aw += __shfl_down(aw, 8);
    ax += __shfl_down(ax, 16); ay += __shfl_down(ay, 16);
    az += __shfl_down(az, 16); aw += __shfl_down(aw, 16);

    float s0 = 0.f, s1 = 0.f, s2 = 0.f, s3 = 0.f;
    float r0 = 0.f, r1 = 0.f, r2 = 0.f, r3 = 0.f;
    if (n < N && sub == 0) {
        float scv[4] = {1.f, 1.f, 1.f, 1.f}, shv[4] = {0.f, 0.f, 0.f, 0.f};
        if (do_bn) {
            #pragma unroll
            for (int j = 0; j < 4; ++j) {
                const int c = p * 4 + j;
                const float mn = statsPrev[c * SSTRIDE] * invN;
                const float var = statsPrev[1024 + c * SSTRIDE] * invN - mn * mn;
                const float rs = rsqrtf(var + EPSV) * gPrev[c];
                scv[j] = rs;
                shv[j] = bPrev[c] - mn * rs;
            }
        }
        float4 z = z4[idx];                  // skip value from k_project
        z.x += ax; z.y += ay; z.z += az; z.w += aw;
        if (do_leaky) {
            z.x = z.x >= 0.f ? z.x : SLOPE * z.x;
            z.y = z.y >= 0.f ? z.y : SLOPE * z.y;
            z.z = z.z >= 0.f ? z.z : SLOPE * z.z;
            z.w = z.w >= 0.f ? z.w : SLOPE * z.w;
        }
        const float4 hz = zprev4[idx];
        z.x += hz.x * scv[0] + shv[0];
        z.y += hz.y * scv[1] + shv[1];
        z.z += hz.z * scv[2] + shv[2];
        z.w += hz.w * scv[3] + shv[3];
        z4[idx] = z;
        s0 = z.x; s1 = z.y; s2 = z.z; s3 = z.w;
        r0 = z.x * z.x; r1 = z.y * z.y; r2 = z.z * z.z; r3 = z.w * z.w;
    }
    // stats reduce: sums across all lanes with equal p (zeros from sub!=0)
    #pragma unroll
    for (int d = 8; d < 64; d <<= 1) {
        s0 += __shfl_down(s0, d); s1 += __shfl_down(s1, d);
        s2 += __shfl_down(s2, d); s3 += __shfl_down(s3, d);
        r0 += __shfl_down(r0, d); r1 += __shfl_down(r1, d);
        r2 += __shfl_down(r2, d); r3 += __shfl_down(r3, d);
    }
    __shared__ float sm[4][DCH], sq[4][DCH];
    if (lane < 8) {
        sm[w][p * 4 + 0] = s0; sm[w][p * 4 + 1] = s1; sm[w][p * 4 + 2] = s2; sm[w][p * 4 + 3] = s3;
        sq[w][p * 4 + 0] = r0; sq[w][p * 4 + 1] = r1; sq[w][p * 4 + 2] = r2; sq[w][p * 4 + 3] = r3;
    }
    __syncthreads();
    if (t < DCH) {
        const float a = sm[0][t] + sm[1][t] + sm[2][t] + sm[3][t];
        const float b = sq[0][t] + sq[1][t] + sq[2][t] + sq[3][t];
        atomicAdd(&statsCur[t * SSTRIDE], a);
        atomicAdd(&statsCur[1024 + t * SSTRIDE], b);
    }
}

// ---------------- final batchnorm apply ----------------
__global__ __launch_bounds__(256) void k_bn(
    const float* __restrict__ z, const float* __restrict__ stats,
    const float* __restrict__ gamma, const float* __restrict__ beta,
    float* __restrict__ out, int total, float invN)
{
    const int i = blockIdx.x * 256 + threadIdx.x;
    if (i >= total) return;
    const int c = i & 31;
    const float mean = stats[c * SSTRIDE] * invN;
    const float var  = stats[1024 + c * SSTRIDE] * invN - mean * mean;
    out[i] = (z[i] - mean) * rsqrtf(var + EPSV) * gamma[c] + beta[c];
}

extern "C" void kernel_launch(void* const* d_in, const int* in_sizes, int n_in,
                              void* d_out, int out_size, void* d_ws, size_t ws_size,
                              hipStream_t stream) {
    const float* x     = (const float*)d_in[0];
    const int*   ei    = (const int*)  d_in[1];
    const float* Wk    = (const float*)d_in[3];
    const float* bk    = (const float*)d_in[4];
    const float* Wq    = (const float*)d_in[5];
    const float* bq    = (const float*)d_in[6];
    const float* Wv    = (const float*)d_in[7];
    const float* bv    = (const float*)d_in[8];
    const float* Ws    = (const float*)d_in[9];
    const float* bs    = (const float*)d_in[10];
    const float* gamma = (const float*)d_in[11];
    const float* beta  = (const float*)d_in[12];

    const int N = in_sizes[0] / DCH;
    const int E = in_sizes[1] / 2;
    const int NB = (N + BSZ - 1) >> BSH;
    const int* src = ei;
    const int* dst = ei + E;

    float* ws     = (float*)d_ws;
    float* kbuf   = ws;                                   // N*32 f32 (pre-scaled -log2e*k)
    unsigned short* qvbuf = (unsigned short*)(kbuf + (size_t)N * DCH);   // N*64 u16
    float* zA     = (float*)qvbuf + (size_t)N * DCH;      // N*32 f32
    float* zB     = zA + (size_t)N * DCH;
    float* statsA = zB + (size_t)N * DCH;                 // 2048
    float* statsB = statsA + 2048;                        // 2048
    int*   deg    = (int*)(statsB + 2048);                // N
    int*   off    = deg + N;                              // N
    int*   bcnt   = off + N;                              // NB
    int*   boff   = bcnt + NB;                            // NB+1
    int*   cur    = boff + NB + 1;                        // NB
    unsigned int* pairs = (unsigned int*)(cur + NB);      // E
    int*   ssrc   = (int*)(pairs + E);                    // E

    const int total = N * DCH;
    const float invN = 1.f / (float)N;

    // ---- build CSR once per launch ----
    hipMemsetAsync(bcnt, 0, (size_t)NB * sizeof(int), stream);
    hipMemsetAsync(cur, 0, (size_t)NB * sizeof(int), stream);
    const int nchunk = (E + CHUNK - 1) / CHUNK;
    k_bucket_hist<<<nchunk, 256, 0, stream>>>(dst, bcnt, E, NB);
    k_scan<<<1, 1024, 0, stream>>>(bcnt, boff, NB);
    k_bucket_scatter<<<nchunk, 256, 0, stream>>>(src, dst, boff, cur, pairs, E, NB);
    k_build_csr<<<NB, 256, 0, stream>>>(pairs, boff, deg, off, ssrc, N);

    const float* zprev = x;
    const float* statsPrev = nullptr;
    for (int l = 0; l < 3; ++l) {
        const size_t wo = (size_t)l * DCH * DCH;
        const size_t bo = (size_t)l * DCH;
        float* zcur = (l & 1) ? zB : zA;
        float* statsCur = (l & 1) ? statsB : statsA;
        const float* gPrev = (l > 0) ? gamma + (size_t)(l - 1) * DCH : gamma;
        const float* bPrev = (l > 0) ? beta + (size_t)(l - 1) * DCH : beta;
        const int do_bn = (l > 0) ? 1 : 0;
        const float* sPrev = do_bn ? statsPrev : statsA;

        k_project<<<(N + 7) / 8, 256, 0, stream>>>(
            zprev, sPrev, gPrev, bPrev,
            Wk + wo, bk + bo, Wq + wo, bq + bo, Wv + wo, bv + bo, Ws + wo, bs + bo,
            kbuf, (uint4*)qvbuf, zcur, statsCur, N, do_bn, invN);
        k_edges_csr<<<(N + 7) / 8, 256, 0, stream>>>(
            off, deg, ssrc, (const float4*)kbuf, (const uint4*)qvbuf,
            (const float4*)zprev, sPrev, gPrev, bPrev,
            (float4*)zcur, statsCur, N, (l < 2) ? 1 : 0, do_bn, invN);

        statsPrev = statsCur;
        zprev = zcur;
    }
    k_bn<<<(total + 255) / 256, 256, 0, stream>>>(
        zA, statsA, gamma + 2 * DCH, beta + 2 * DCH, (float*)d_out, total, invN);
}

// Round 9
// 828.191 us; speedup vs baseline: 2.7170x; 1.4164x over previous
//
#include <hip/hip_runtime.h>

#define DCH 32
#define EPSV 1e-5f
#define SLOPE 0.01f
#define SSTRIDE 16       // stats stride in floats (64B/channel slot)
#define BSH 7            // bucket shift: 128 nodes per dst bucket
#define BSZ 128
#define NSG 32           // src groups per bucket (approximate src sort granularity)
#define LOG2E 1.4426950408889634f

#if defined(__has_builtin)
#  if __has_builtin(__builtin_amdgcn_exp2f)
#    define EXP2F(x) __builtin_amdgcn_exp2f(x)
#  endif
#  if __has_builtin(__builtin_amdgcn_rcpf)
#    define RCPF(x) __builtin_amdgcn_rcpf(x)
#  endif
#endif
#ifndef EXP2F
#  define EXP2F(x) exp2f(x)
#endif
#ifndef RCPF
#  define RCPF(x) (1.0f / (x))
#endif

__device__ __forceinline__ unsigned short f2bf(float x) {
    unsigned u = __float_as_uint(x);
    unsigned r = (u + 0x7FFFu + ((u >> 16) & 1u)) >> 16;   // RNE
    return (unsigned short)r;
}

// ---------------- 2D histogram over (dst-bucket, src-group) ----------------
__global__ __launch_bounds__(256) void k_hist2(const int* __restrict__ src, const int* __restrict__ dst,
                                               int* __restrict__ cnt, int E, int SGS) {
    const int e = blockIdx.x * 256 + threadIdx.x;
    if (e < E) atomicAdd(&cnt[(dst[e] >> BSH) * NSG + (src[e] >> SGS)], 1);
}

// ---------------- single-block chunked exclusive scan (M values -> off[0..M]) ----------------
__global__ __launch_bounds__(1024) void k_scan(const int* __restrict__ deg, int* __restrict__ off, int N) {
    __shared__ int wsum[16];
    __shared__ int woff[16];
    __shared__ int ctot;
    __shared__ int carry;
    const int t = threadIdx.x;
    const int lane = t & 63;
    const int w = t >> 6;
    if (t == 0) carry = 0;
    __syncthreads();
    for (int base = 0; base < N; base += 1024) {
        const int i = base + t;
        const int v = (i < N) ? deg[i] : 0;
        int incl = v;
        #pragma unroll
        for (int d = 1; d < 64; d <<= 1) {
            int tmp = __shfl_up(incl, d);
            if (lane >= d) incl += tmp;
        }
        if (lane == 63) wsum[w] = incl;
        __syncthreads();
        if (t < 16) {
            const int a = wsum[t];
            int in = a;
            #pragma unroll
            for (int d = 1; d < 16; d <<= 1) {
                int tmp = __shfl_up(in, d);
                if (t >= d) in += tmp;
            }
            woff[t] = in - a;
            if (t == 15) ctot = in;
        }
        __syncthreads();
        if (i < N) off[i] = carry + woff[w] + incl - v;
        __syncthreads();
        if (t == 0) carry += ctot;
        __syncthreads();
    }
    if (t == 0) off[N] = carry;
}

// ---------------- scatter into (bucket, src-group) segments ----------------
__global__ __launch_bounds__(256) void k_scatter2(const int* __restrict__ src, const int* __restrict__ dst,
                                                  const int* __restrict__ boff2, int* __restrict__ cur2,
                                                  unsigned int* __restrict__ pairs, int E, int SGS) {
    const int e = blockIdx.x * 256 + threadIdx.x;
    if (e < E) {
        const int s = src[e];
        const int d = dst[e];
        const int key = (d >> BSH) * NSG + (s >> SGS);
        const int r = atomicAdd(&cur2[key], 1);
        pairs[boff2[key] + r] = ((unsigned)s << BSH) | (unsigned)(d & (BSZ - 1));
    }
}

// ---------------- per-bucket CSR build, src-group-ordered node lists ----------------
// Bucket b's edges live in pairs[boff2[b*NSG] .. boff2[(b+1)*NSG]), grouped by sg.
// Produce ssrc with each node's list contiguous and grouped by sg ascending.
__global__ __launch_bounds__(256) void k_build_csr2(const unsigned int* __restrict__ pairs,
                                                    const int* __restrict__ boff2,
                                                    int* __restrict__ deg, int* __restrict__ off,
                                                    int* __restrict__ ssrc, int N, int SGS) {
    __shared__ int cnt2[BSZ * NSG];     // 16 KB
    __shared__ int scn2[BSZ * NSG];     // 16 KB
    __shared__ int rs[BSZ];
    __shared__ int ex[BSZ];
    const int t = threadIdx.x;
    const int b = blockIdx.x;
    const int begin = boff2[b * NSG];
    const int end   = boff2[(b + 1) * NSG];
    for (int i = t; i < BSZ * NSG; i += 256) cnt2[i] = 0;
    __syncthreads();
    // 2D histogram (dst_local, src-group)
    for (int i = begin + t; i < end; i += 256) {
        const unsigned u = pairs[i];
        const int dl = u & (BSZ - 1);
        const int sg = (u >> BSH) >> SGS;
        atomicAdd(&cnt2[dl * NSG + sg], 1);
    }
    __syncthreads();
    // row prefix (exclusive within each dl) + row sums
    if (t < BSZ) {
        int acc = 0;
        #pragma unroll
        for (int sg = 0; sg < NSG; ++sg) {
            scn2[t * NSG + sg] = acc;
            acc += cnt2[t * NSG + sg];
        }
        rs[t] = acc;
    }
    __syncthreads();
    // scan of row sums -> node base offsets
    if (t < BSZ) ex[t] = rs[t];
    __syncthreads();
    #pragma unroll
    for (int s = 1; s < BSZ; s <<= 1) {
        int add = 0;
        if (t < BSZ && t >= s) add = ex[t - s];
        __syncthreads();
        if (t < BSZ) ex[t] += add;
        __syncthreads();
    }
    const int node0 = b << BSH;
    if (t < BSZ) {
        const int base = begin + ex[t] - rs[t];   // exclusive
        if (node0 + t < N) {
            deg[node0 + t] = rs[t];
            off[node0 + t] = base;
        }
        #pragma unroll
        for (int sg = 0; sg < NSG; ++sg) scn2[t * NSG + sg] += base;
    }
    __syncthreads();
    // stable-by-group scatter into global ssrc (positions span a ~16KB window)
    for (int i = begin + t; i < end; i += 256) {
        const unsigned u = pairs[i];
        const int dl = u & (BSZ - 1);
        const int sg = (u >> BSH) >> SGS;
        const int pos = atomicAdd(&scn2[dl * NSG + sg], 1);
        ssrc[pos] = (int)(u >> BSH);
    }
}

// ---------------- fused: [BN of prev layer] + 4-way projection ----------------
__global__ __launch_bounds__(256) void k_project(
    const float* __restrict__ xin,
    const float* __restrict__ statsPrev, const float* __restrict__ gPrev, const float* __restrict__ bPrev,
    const float* __restrict__ Wk, const float* __restrict__ bk,
    const float* __restrict__ Wq, const float* __restrict__ bq,
    const float* __restrict__ Wv, const float* __restrict__ bv,
    const float* __restrict__ Ws, const float* __restrict__ bs,
    float* __restrict__ kout, uint4* __restrict__ qvout,
    float* __restrict__ zout, float* __restrict__ statsCur,
    int N, int do_bn, float invN)
{
    __shared__ float wk[DCH][DCH + 1], wq[DCH][DCH + 1], wv[DCH][DCH + 1], wsk[DCH][DCH + 1];
    __shared__ float xs[8][DCH];
    __shared__ unsigned short qvs[8][64];
    const int t = threadIdx.x;
    if (blockIdx.x == 0) {
        for (int i = t; i < 2048; i += 256) statsCur[i] = 0.f;
    }
    for (int i = t; i < DCH * DCH; i += 256) {
        const int c = i >> 5, d = i & 31;
        wk[c][d] = Wk[i];
        wq[c][d] = Wq[i];
        wv[c][d] = Wv[i];
        wsk[c][d] = Ws[i];
    }
    const int li = t >> 5;
    const int c  = t & 31;
    const int node = blockIdx.x * 8 + li;
    if (node < N) {
        float xv = xin[node * DCH + c];
        if (do_bn) {
            const float mn = statsPrev[c * SSTRIDE] * invN;
            const float var = statsPrev[1024 + c * SSTRIDE] * invN - mn * mn;
            const float sc = rsqrtf(var + EPSV) * gPrev[c];
            xv = (xv - mn) * sc + bPrev[c];
        }
        xs[li][c] = xv;
    }
    __syncthreads();
    if (node < N) {
        float aK = 0.f, aQ = 0.f, aV = 0.f, aS = 0.f;
        #pragma unroll
        for (int d = 0; d < DCH; ++d) {
            const float xv = xs[li][d];
            aK += xv * wk[c][d];
            aQ += xv * wq[c][d];
            aV += xv * wv[c][d];
            aS += xv * wsk[c][d];
        }
        const int o = node * DCH + c;
        kout[o] = -LOG2E * (aK + bk[c]);
        zout[o] = aS + bs[c];
        const int g = c >> 2, j = c & 3;
        qvs[li][g * 8 + j]     = f2bf(-LOG2E * (aQ + bq[c]));
        qvs[li][g * 8 + 4 + j] = f2bf(aV + bv[c]);
    }
    __syncthreads();
    if (t < 64) {
        const int ln = t >> 3, g = t & 7;
        const int nd = blockIdx.x * 8 + ln;
        if (nd < N) qvout[nd * 8 + g] = ((const uint4*)qvs[ln])[g];
    }
}

// gate accumulate helper: acc += v * sigmoid (exp2 form, kn/qn pre-scaled by -log2e)
#define GATE_ACC(u, ax, ay, az, aw)                                          \
    do {                                                                     \
        const float q0 = __uint_as_float((u).x << 16);                       \
        const float q1 = __uint_as_float((u).x & 0xffff0000u);               \
        const float q2 = __uint_as_float((u).y << 16);                       \
        const float q3 = __uint_as_float((u).y & 0xffff0000u);               \
        const float v0 = __uint_as_float((u).z << 16);                       \
        const float v1 = __uint_as_float((u).z & 0xffff0000u);               \
        const float v2 = __uint_as_float((u).w << 16);                       \
        const float v3 = __uint_as_float((u).w & 0xffff0000u);               \
        ax = fmaf(v0, RCPF(1.f + EXP2F(kn.x + q0)), ax);                     \
        ay = fmaf(v1, RCPF(1.f + EXP2F(kn.y + q1)), ay);                     \
        az = fmaf(v2, RCPF(1.f + EXP2F(kn.z + q2)), az);                     \
        aw = fmaf(v3, RCPF(1.f + EXP2F(kn.w + q3)), aw);                     \
    } while (0)

// ---------------- dst-centric gather + gate + fused [BN(prev) residual]/leaky/stats ----------------
// (R6-proven structure: 8 lanes per node, 32 nodes/block, unroll x4 contiguous)
__global__ __launch_bounds__(256) void k_edges_csr(
    const int* __restrict__ off, const int* __restrict__ deg, const int* __restrict__ ssrc,
    const float4* __restrict__ kn4, const uint4* __restrict__ qv4,
    const float4* __restrict__ zprev4,
    const float* __restrict__ statsPrev, const float* __restrict__ gPrev, const float* __restrict__ bPrev,
    float4* __restrict__ z4,
    float* __restrict__ statsCur, int N, int do_leaky, int do_bn, float invN)
{
    const int t = threadIdx.x;
    const int p = t & 7;
    const int lane = t & 63;
    const int w = t >> 6;
    float scv[4] = {1.f, 1.f, 1.f, 1.f}, shv[4] = {0.f, 0.f, 0.f, 0.f};
    if (do_bn) {
        #pragma unroll
        for (int j = 0; j < 4; ++j) {
            const int c = p * 4 + j;
            const float mn = statsPrev[c * SSTRIDE] * invN;
            const float var = statsPrev[1024 + c * SSTRIDE] * invN - mn * mn;
            const float rs = rsqrtf(var + EPSV) * gPrev[c];
            scv[j] = rs;
            shv[j] = bPrev[c] - mn * rs;
        }
    }
    float s0 = 0.f, s1 = 0.f, s2 = 0.f, s3 = 0.f;
    float r0 = 0.f, r1 = 0.f, r2 = 0.f, r3 = 0.f;
    const int n = blockIdx.x * 32 + (t >> 3);
    if (n < N) {
        const int idx = n * 8 + p;
        const float4 kn = kn4[idx];
        float ax = 0.f, ay = 0.f, az = 0.f, aw = 0.f;
        float bx = 0.f, by = 0.f, bz = 0.f, bw = 0.f;
        const int beg = off[n];
        const int end = beg + deg[n];
        int e = beg;
        // unroll x4: 4 independent gathers in flight per lane
        for (; e + 4 <= end; e += 4) {
            const int sA = ssrc[e];
            const int sB = ssrc[e + 1];
            const int sC = ssrc[e + 2];
            const int sD = ssrc[e + 3];
            const uint4 uA = qv4[(size_t)sA * 8 + p];
            const uint4 uB = qv4[(size_t)sB * 8 + p];
            const uint4 uC = qv4[(size_t)sC * 8 + p];
            const uint4 uD = qv4[(size_t)sD * 8 + p];
            GATE_ACC(uA, ax, ay, az, aw);
            GATE_ACC(uB, bx, by, bz, bw);
            GATE_ACC(uC, ax, ay, az, aw);
            GATE_ACC(uD, bx, by, bz, bw);
        }
        for (; e < end; ++e) {
            const int s = ssrc[e];
            const uint4 u = qv4[(size_t)s * 8 + p];
            GATE_ACC(u, ax, ay, az, aw);
        }
        ax += bx; ay += by; az += bz; aw += bw;
        float4 z = z4[idx];                  // skip value from k_project
        z.x += ax; z.y += ay; z.z += az; z.w += aw;
        if (do_leaky) {
            z.x = z.x >= 0.f ? z.x : SLOPE * z.x;
            z.y = z.y >= 0.f ? z.y : SLOPE * z.y;
            z.z = z.z >= 0.f ? z.z : SLOPE * z.z;
            z.w = z.w >= 0.f ? z.w : SLOPE * z.w;
        }
        const float4 hz = zprev4[idx];
        z.x += hz.x * scv[0] + shv[0];
        z.y += hz.y * scv[1] + shv[1];
        z.z += hz.z * scv[2] + shv[2];
        z.w += hz.w * scv[3] + shv[3];
        z4[idx] = z;
        s0 = z.x; s1 = z.y; s2 = z.z; s3 = z.w;
        r0 = z.x * z.x; r1 = z.y * z.y; r2 = z.z * z.z; r3 = z.w * z.w;
    }
    #pragma unroll
    for (int d = 8; d < 64; d <<= 1) {
        s0 += __shfl_down(s0, d); s1 += __shfl_down(s1, d);
        s2 += __shfl_down(s2, d); s3 += __shfl_down(s3, d);
        r0 += __shfl_down(r0, d); r1 += __shfl_down(r1, d);
        r2 += __shfl_down(r2, d); r3 += __shfl_down(r3, d);
    }
    __shared__ float sm[4][DCH], sq[4][DCH];
    if (lane < 8) {
        sm[w][p * 4 + 0] = s0; sm[w][p * 4 + 1] = s1; sm[w][p * 4 + 2] = s2; sm[w][p * 4 + 3] = s3;
        sq[w][p * 4 + 0] = r0; sq[w][p * 4 + 1] = r1; sq[w][p * 4 + 2] = r2; sq[w][p * 4 + 3] = r3;
    }
    __syncthreads();
    if (t < DCH) {
        const float a = sm[0][t] + sm[1][t] + sm[2][t] + sm[3][t];
        const float b = sq[0][t] + sq[1][t] + sq[2][t] + sq[3][t];
        atomicAdd(&statsCur[t * SSTRIDE], a);
        atomicAdd(&statsCur[1024 + t * SSTRIDE], b);
    }
}

// ---------------- final batchnorm apply ----------------
__global__ __launch_bounds__(256) void k_bn(
    const float* __restrict__ z, const float* __restrict__ stats,
    const float* __restrict__ gamma, const float* __restrict__ beta,
    float* __restrict__ out, int total, float invN)
{
    const int i = blockIdx.x * 256 + threadIdx.x;
    if (i >= total) return;
    const int c = i & 31;
    const float mean = stats[c * SSTRIDE] * invN;
    const float var  = stats[1024 + c * SSTRIDE] * invN - mean * mean;
    out[i] = (z[i] - mean) * rsqrtf(var + EPSV) * gamma[c] + beta[c];
}

extern "C" void kernel_launch(void* const* d_in, const int* in_sizes, int n_in,
                              void* d_out, int out_size, void* d_ws, size_t ws_size,
                              hipStream_t stream) {
    const float* x     = (const float*)d_in[0];
    const int*   ei    = (const int*)  d_in[1];
    const float* Wk    = (const float*)d_in[3];
    const float* bk    = (const float*)d_in[4];
    const float* Wq    = (const float*)d_in[5];
    const float* bq    = (const float*)d_in[6];
    const float* Wv    = (const float*)d_in[7];
    const float* bv    = (const float*)d_in[8];
    const float* Ws    = (const float*)d_in[9];
    const float* bs    = (const float*)d_in[10];
    const float* gamma = (const float*)d_in[11];
    const float* beta  = (const float*)d_in[12];

    const int N = in_sizes[0] / DCH;
    const int E = in_sizes[1] / 2;
    const int NB = (N + BSZ - 1) >> BSH;
    const int M  = NB * NSG;                 // (bucket, src-group) segments
    int SGS = 0;
    while (((N - 1) >> SGS) >= NSG) SGS++;   // src group shift
    const int* src = ei;
    const int* dst = ei + E;

    float* ws     = (float*)d_ws;
    float* kbuf   = ws;                                   // N*32 f32 (pre-scaled -log2e*k)
    unsigned short* qvbuf = (unsigned short*)(kbuf + (size_t)N * DCH);   // N*64 u16
    float* zA     = (float*)qvbuf + (size_t)N * DCH;      // N*32 f32
    float* zB     = zA + (size_t)N * DCH;
    float* statsA = zB + (size_t)N * DCH;                 // 2048
    float* statsB = statsA + 2048;                        // 2048
    int*   deg    = (int*)(statsB + 2048);                // N
    int*   off    = deg + N;                              // N
    int*   bcnt2  = off + N;                              // M
    int*   boff2  = bcnt2 + M;                            // M+1
    int*   cur2   = boff2 + M + 1;                        // M
    unsigned int* pairs = (unsigned int*)(cur2 + M);      // E
    int*   ssrc   = (int*)(pairs + E);                    // E

    const int total = N * DCH;
    const float invN = 1.f / (float)N;

    // ---- build src-group-ordered CSR once per launch ----
    hipMemsetAsync(bcnt2, 0, (size_t)M * sizeof(int), stream);
    hipMemsetAsync(cur2, 0, (size_t)M * sizeof(int), stream);
    k_hist2<<<(E + 255) / 256, 256, 0, stream>>>(src, dst, bcnt2, E, SGS);
    k_scan<<<1, 1024, 0, stream>>>(bcnt2, boff2, M);
    k_scatter2<<<(E + 255) / 256, 256, 0, stream>>>(src, dst, boff2, cur2, pairs, E, SGS);
    k_build_csr2<<<NB, 256, 0, stream>>>(pairs, boff2, deg, off, ssrc, N, SGS);

    const float* zprev = x;
    const float* statsPrev = nullptr;
    for (int l = 0; l < 3; ++l) {
        const size_t wo = (size_t)l * DCH * DCH;
        const size_t bo = (size_t)l * DCH;
        float* zcur = (l & 1) ? zB : zA;
        float* statsCur = (l & 1) ? statsB : statsA;
        const float* gPrev = (l > 0) ? gamma + (size_t)(l - 1) * DCH : gamma;
        const float* bPrev = (l > 0) ? beta + (size_t)(l - 1) * DCH : beta;
        const int do_bn = (l > 0) ? 1 : 0;
        const float* sPrev = do_bn ? statsPrev : statsA;

        k_project<<<(N + 7) / 8, 256, 0, stream>>>(
            zprev, sPrev, gPrev, bPrev,
            Wk + wo, bk + bo, Wq + wo, bq + bo, Wv + wo, bv + bo, Ws + wo, bs + bo,
            kbuf, (uint4*)qvbuf, zcur, statsCur, N, do_bn, invN);
        k_edges_csr<<<(N + 31) / 32, 256, 0, stream>>>(
            off, deg, ssrc, (const float4*)kbuf, (const uint4*)qvbuf,
            (const float4*)zprev, sPrev, gPrev, bPrev,
            (float4*)zcur, statsCur, N, (l < 2) ? 1 : 0, do_bn, invN);

        statsPrev = statsCur;
        zprev = zcur;
    }
    k_bn<<<(total + 255) / 256, 256, 0, stream>>>(
        zA, statsA, gamma + 2 * DCH, beta + 2 * DCH, (float*)d_out, total, invN);
}

// Round 10
// 550.024 us; speedup vs baseline: 4.0911x; 1.5057x over previous
//
#include <hip/hip_runtime.h>

#define DCH 32
#define EPSV 1e-5f
#define SLOPE 0.01f
#define SSTRIDE 16       // stats stride in floats (64B/channel slot)
#define BSH 7            // bucket shift: 128 nodes per dst bucket
#define BSZ 128
#define NBMAX 1024       // max buckets handled by LDS paths (N <= 131072)
#define CHUNK 8192       // edges per block in hist/scatter
#define NSG 32           // src groups per bucket (approximate src sort granularity)
#define NSGP 33          // padded row stride for in-LDS 2D counters (bank-conflict-free row scan)
#define LOG2E 1.4426950408889634f

#if defined(__has_builtin)
#  if __has_builtin(__builtin_amdgcn_exp2f)
#    define EXP2F(x) __builtin_amdgcn_exp2f(x)
#  endif
#  if __has_builtin(__builtin_amdgcn_rcpf)
#    define RCPF(x) __builtin_amdgcn_rcpf(x)
#  endif
#endif
#ifndef EXP2F
#  define EXP2F(x) exp2f(x)
#endif
#ifndef RCPF
#  define RCPF(x) (1.0f / (x))
#endif

__device__ __forceinline__ unsigned short f2bf(float x) {
    unsigned u = __float_as_uint(x);
    unsigned r = (u + 0x7FFFu + ((u >> 16) & 1u)) >> 16;   // RNE
    return (unsigned short)r;
}

// ---------------- bucket histogram (LDS-staged, dst-bucket only) ----------------
__global__ __launch_bounds__(256) void k_bucket_hist(const int* __restrict__ dst,
                                                     int* __restrict__ bcnt, int E, int NB) {
    __shared__ int h[NBMAX];
    const int t = threadIdx.x;
    const int e0 = blockIdx.x * CHUNK;
    const int e1 = min(e0 + CHUNK, E);
    if (NB <= NBMAX) {
        for (int j = t; j < NB; j += 256) h[j] = 0;
        __syncthreads();
        for (int e = e0 + t; e < e1; e += 256) atomicAdd(&h[dst[e] >> BSH], 1);
        __syncthreads();
        for (int j = t; j < NB; j += 256) if (h[j]) atomicAdd(&bcnt[j], h[j]);
    } else {
        for (int e = e0 + t; e < e1; e += 256) atomicAdd(&bcnt[dst[e] >> BSH], 1);
    }
}

// ---------------- single-block chunked exclusive scan ----------------
__global__ __launch_bounds__(1024) void k_scan(const int* __restrict__ deg, int* __restrict__ off, int N) {
    __shared__ int wsum[16];
    __shared__ int woff[16];
    __shared__ int ctot;
    __shared__ int carry;
    const int t = threadIdx.x;
    const int lane = t & 63;
    const int w = t >> 6;
    if (t == 0) carry = 0;
    __syncthreads();
    for (int base = 0; base < N; base += 1024) {
        const int i = base + t;
        const int v = (i < N) ? deg[i] : 0;
        int incl = v;
        #pragma unroll
        for (int d = 1; d < 64; d <<= 1) {
            int tmp = __shfl_up(incl, d);
            if (lane >= d) incl += tmp;
        }
        if (lane == 63) wsum[w] = incl;
        __syncthreads();
        if (t < 16) {
            const int a = wsum[t];
            int in = a;
            #pragma unroll
            for (int d = 1; d < 16; d <<= 1) {
                int tmp = __shfl_up(in, d);
                if (t >= d) in += tmp;
            }
            woff[t] = in - a;
            if (t == 15) ctot = in;
        }
        __syncthreads();
        if (i < N) off[i] = carry + woff[w] + incl - v;
        __syncthreads();
        if (t == 0) carry += ctot;
        __syncthreads();
    }
    if (t == 0) off[N] = carry;
}

// ---------------- bucket scatter: packed (src<<7)|dst_local into dense bucket runs ----------------
__global__ __launch_bounds__(256) void k_bucket_scatter(const int* __restrict__ src, const int* __restrict__ dst,
                                                        const int* __restrict__ boff, int* __restrict__ cur,
                                                        unsigned int* __restrict__ pairs, int E, int NB) {
    const int t = threadIdx.x;
    const int e0 = blockIdx.x * CHUNK;
    const int e1 = min(e0 + CHUNK, E);
    if (NB <= NBMAX) {
        __shared__ int cnt[NBMAX];
        __shared__ int base[NBMAX];
        for (int j = t; j < NB; j += 256) { cnt[j] = 0; }
        __syncthreads();
        for (int e = e0 + t; e < e1; e += 256) atomicAdd(&cnt[dst[e] >> BSH], 1);
        __syncthreads();
        for (int j = t; j < NB; j += 256) {
            const int c = cnt[j];
            if (c) base[j] = atomicAdd(&cur[j], c);
            cnt[j] = 0;          // reuse as rank counter
        }
        __syncthreads();
        for (int e = e0 + t; e < e1; e += 256) {
            const int d = dst[e];
            const int bk = d >> BSH;
            const int r = atomicAdd(&cnt[bk], 1);
            pairs[boff[bk] + base[bk] + r] = ((unsigned)src[e] << BSH) | (unsigned)(d & (BSZ - 1));
        }
    } else {
        for (int e = e0 + t; e < e1; e += 256) {
            const int d = dst[e];
            const int bk = d >> BSH;
            const int r = atomicAdd(&cur[bk], 1);
            pairs[boff[bk] + r] = ((unsigned)src[e] << BSH) | (unsigned)(d & (BSZ - 1));
        }
    }
}

// ---------------- per-bucket CSR build with in-LDS src-group ordering ----------------
// Bucket b's edges: pairs[boff[b] .. boff[b+1]). Produce per-node contiguous lists
// ordered by src-group ascending (approximate src sort -> L2-friendly gathers).
// 2D counters live in one padded LDS array (~17 KB).
__global__ __launch_bounds__(256) void k_build_csr2(const unsigned int* __restrict__ pairs,
                                                    const int* __restrict__ boff,
                                                    int* __restrict__ deg, int* __restrict__ off,
                                                    int* __restrict__ ssrc, int N, int SGS) {
    __shared__ int cnt2[BSZ * NSGP];    // ~17 KB, row-padded
    __shared__ int rs[BSZ];
    __shared__ int ex[BSZ];
    const int t = threadIdx.x;
    const int b = blockIdx.x;
    const int begin = boff[b], end = boff[b + 1];
    for (int i = t; i < BSZ * NSGP; i += 256) cnt2[i] = 0;
    __syncthreads();
    // 2D histogram (dst_local, src-group)
    for (int i = begin + t; i < end; i += 256) {
        const unsigned u = pairs[i];
        atomicAdd(&cnt2[(int)(u & (BSZ - 1)) * NSGP + (int)((u >> BSH) >> SGS)], 1);
    }
    __syncthreads();
    // in-place exclusive row prefix (thread t owns row t; padded stride -> no bank conflict)
    if (t < BSZ) {
        int acc = 0;
        #pragma unroll
        for (int sg = 0; sg < NSG; ++sg) {
            const int c = cnt2[t * NSGP + sg];
            cnt2[t * NSGP + sg] = acc;
            acc += c;
        }
        rs[t] = acc;
        ex[t] = acc;
    }
    __syncthreads();
    #pragma unroll
    for (int s = 1; s < BSZ; s <<= 1) {
        int add = 0;
        if (t < BSZ && t >= s) add = ex[t - s];
        __syncthreads();
        if (t < BSZ) ex[t] += add;
        __syncthreads();
    }
    const int node0 = b << BSH;
    if (t < BSZ) {
        const int base = begin + ex[t] - rs[t];   // node's global base offset
        if (node0 + t < N) {
            deg[node0 + t] = rs[t];
            off[node0 + t] = base;
        }
        #pragma unroll
        for (int sg = 0; sg < NSG; ++sg) cnt2[t * NSGP + sg] += base;
    }
    __syncthreads();
    // stable-by-group scatter into the bucket's contiguous ssrc window (~16 KB, L2-absorbed)
    for (int i = begin + t; i < end; i += 256) {
        const unsigned u = pairs[i];
        const int pos = atomicAdd(&cnt2[(int)(u & (BSZ - 1)) * NSGP + (int)((u >> BSH) >> SGS)], 1);
        ssrc[pos] = (int)(u >> BSH);
    }
}

// ---------------- fused: [BN of prev layer] + 4-way projection ----------------
__global__ __launch_bounds__(256) void k_project(
    const float* __restrict__ xin,
    const float* __restrict__ statsPrev, const float* __restrict__ gPrev, const float* __restrict__ bPrev,
    const float* __restrict__ Wk, const float* __restrict__ bk,
    const float* __restrict__ Wq, const float* __restrict__ bq,
    const float* __restrict__ Wv, const float* __restrict__ bv,
    const float* __restrict__ Ws, const float* __restrict__ bs,
    float* __restrict__ kout, uint4* __restrict__ qvout,
    float* __restrict__ zout, float* __restrict__ statsCur,
    int N, int do_bn, float invN)
{
    __shared__ float wk[DCH][DCH + 1], wq[DCH][DCH + 1], wv[DCH][DCH + 1], wsk[DCH][DCH + 1];
    __shared__ float xs[8][DCH];
    __shared__ unsigned short qvs[8][64];
    const int t = threadIdx.x;
    if (blockIdx.x == 0) {
        for (int i = t; i < 2048; i += 256) statsCur[i] = 0.f;
    }
    for (int i = t; i < DCH * DCH; i += 256) {
        const int c = i >> 5, d = i & 31;
        wk[c][d] = Wk[i];
        wq[c][d] = Wq[i];
        wv[c][d] = Wv[i];
        wsk[c][d] = Ws[i];
    }
    const int li = t >> 5;
    const int c  = t & 31;
    const int node = blockIdx.x * 8 + li;
    if (node < N) {
        float xv = xin[node * DCH + c];
        if (do_bn) {
            const float mn = statsPrev[c * SSTRIDE] * invN;
            const float var = statsPrev[1024 + c * SSTRIDE] * invN - mn * mn;
            const float sc = rsqrtf(var + EPSV) * gPrev[c];
            xv = (xv - mn) * sc + bPrev[c];
        }
        xs[li][c] = xv;
    }
    __syncthreads();
    if (node < N) {
        float aK = 0.f, aQ = 0.f, aV = 0.f, aS = 0.f;
        #pragma unroll
        for (int d = 0; d < DCH; ++d) {
            const float xv = xs[li][d];
            aK += xv * wk[c][d];
            aQ += xv * wq[c][d];
            aV += xv * wv[c][d];
            aS += xv * wsk[c][d];
        }
        const int o = node * DCH + c;
        kout[o] = -LOG2E * (aK + bk[c]);
        zout[o] = aS + bs[c];
        const int g = c >> 2, j = c & 3;
        qvs[li][g * 8 + j]     = f2bf(-LOG2E * (aQ + bq[c]));
        qvs[li][g * 8 + 4 + j] = f2bf(aV + bv[c]);
    }
    __syncthreads();
    if (t < 64) {
        const int ln = t >> 3, g = t & 7;
        const int nd = blockIdx.x * 8 + ln;
        if (nd < N) qvout[nd * 8 + g] = ((const uint4*)qvs[ln])[g];
    }
}

// gate accumulate helper: acc += v * sigmoid (exp2 form, kn/qn pre-scaled by -log2e)
#define GATE_ACC(u, ax, ay, az, aw)                                          \
    do {                                                                     \
        const float q0 = __uint_as_float((u).x << 16);                       \
        const float q1 = __uint_as_float((u).x & 0xffff0000u);               \
        const float q2 = __uint_as_float((u).y << 16);                       \
        const float q3 = __uint_as_float((u).y & 0xffff0000u);               \
        const float v0 = __uint_as_float((u).z << 16);                       \
        const float v1 = __uint_as_float((u).z & 0xffff0000u);               \
        const float v2 = __uint_as_float((u).w << 16);                       \
        const float v3 = __uint_as_float((u).w & 0xffff0000u);               \
        ax = fmaf(v0, RCPF(1.f + EXP2F(kn.x + q0)), ax);                     \
        ay = fmaf(v1, RCPF(1.f + EXP2F(kn.y + q1)), ay);                     \
        az = fmaf(v2, RCPF(1.f + EXP2F(kn.z + q2)), az);                     \
        aw = fmaf(v3, RCPF(1.f + EXP2F(kn.w + q3)), aw);                     \
    } while (0)

// ---------------- dst-centric gather + gate + fused [BN(prev) residual]/leaky/stats ----------------
// (R6-proven structure: 8 lanes per node, 32 nodes/block, unroll x4 contiguous)
__global__ __launch_bounds__(256) void k_edges_csr(
    const int* __restrict__ off, const int* __restrict__ deg, const int* __restrict__ ssrc,
    const float4* __restrict__ kn4, const uint4* __restrict__ qv4,
    const float4* __restrict__ zprev4,
    const float* __restrict__ statsPrev, const float* __restrict__ gPrev, const float* __restrict__ bPrev,
    float4* __restrict__ z4,
    float* __restrict__ statsCur, int N, int do_leaky, int do_bn, float invN)
{
    const int t = threadIdx.x;
    const int p = t & 7;
    const int lane = t & 63;
    const int w = t >> 6;
    float scv[4] = {1.f, 1.f, 1.f, 1.f}, shv[4] = {0.f, 0.f, 0.f, 0.f};
    if (do_bn) {
        #pragma unroll
        for (int j = 0; j < 4; ++j) {
            const int c = p * 4 + j;
            const float mn = statsPrev[c * SSTRIDE] * invN;
            const float var = statsPrev[1024 + c * SSTRIDE] * invN - mn * mn;
            const float rs = rsqrtf(var + EPSV) * gPrev[c];
            scv[j] = rs;
            shv[j] = bPrev[c] - mn * rs;
        }
    }
    float s0 = 0.f, s1 = 0.f, s2 = 0.f, s3 = 0.f;
    float r0 = 0.f, r1 = 0.f, r2 = 0.f, r3 = 0.f;
    const int n = blockIdx.x * 32 + (t >> 3);
    if (n < N) {
        const int idx = n * 8 + p;
        const float4 kn = kn4[idx];
        float ax = 0.f, ay = 0.f, az = 0.f, aw = 0.f;
        float bx = 0.f, by = 0.f, bz = 0.f, bw = 0.f;
        const int beg = off[n];
        const int end = beg + deg[n];
        int e = beg;
        // unroll x4: 4 independent gathers in flight per lane
        for (; e + 4 <= end; e += 4) {
            const int sA = ssrc[e];
            const int sB = ssrc[e + 1];
            const int sC = ssrc[e + 2];
            const int sD = ssrc[e + 3];
            const uint4 uA = qv4[(size_t)sA * 8 + p];
            const uint4 uB = qv4[(size_t)sB * 8 + p];
            const uint4 uC = qv4[(size_t)sC * 8 + p];
            const uint4 uD = qv4[(size_t)sD * 8 + p];
            GATE_ACC(uA, ax, ay, az, aw);
            GATE_ACC(uB, bx, by, bz, bw);
            GATE_ACC(uC, ax, ay, az, aw);
            GATE_ACC(uD, bx, by, bz, bw);
        }
        for (; e < end; ++e) {
            const int s = ssrc[e];
            const uint4 u = qv4[(size_t)s * 8 + p];
            GATE_ACC(u, ax, ay, az, aw);
        }
        ax += bx; ay += by; az += bz; aw += bw;
        float4 z = z4[idx];                  // skip value from k_project
        z.x += ax; z.y += ay; z.z += az; z.w += aw;
        if (do_leaky) {
            z.x = z.x >= 0.f ? z.x : SLOPE * z.x;
            z.y = z.y >= 0.f ? z.y : SLOPE * z.y;
            z.z = z.z >= 0.f ? z.z : SLOPE * z.z;
            z.w = z.w >= 0.f ? z.w : SLOPE * z.w;
        }
        const float4 hz = zprev4[idx];
        z.x += hz.x * scv[0] + shv[0];
        z.y += hz.y * scv[1] + shv[1];
        z.z += hz.z * scv[2] + shv[2];
        z.w += hz.w * scv[3] + shv[3];
        z4[idx] = z;
        s0 = z.x; s1 = z.y; s2 = z.z; s3 = z.w;
        r0 = z.x * z.x; r1 = z.y * z.y; r2 = z.z * z.z; r3 = z.w * z.w;
    }
    #pragma unroll
    for (int d = 8; d < 64; d <<= 1) {
        s0 += __shfl_down(s0, d); s1 += __shfl_down(s1, d);
        s2 += __shfl_down(s2, d); s3 += __shfl_down(s3, d);
        r0 += __shfl_down(r0, d); r1 += __shfl_down(r1, d);
        r2 += __shfl_down(r2, d); r3 += __shfl_down(r3, d);
    }
    __shared__ float sm[4][DCH], sq[4][DCH];
    if (lane < 8) {
        sm[w][p * 4 + 0] = s0; sm[w][p * 4 + 1] = s1; sm[w][p * 4 + 2] = s2; sm[w][p * 4 + 3] = s3;
        sq[w][p * 4 + 0] = r0; sq[w][p * 4 + 1] = r1; sq[w][p * 4 + 2] = r2; sq[w][p * 4 + 3] = r3;
    }
    __syncthreads();
    if (t < DCH) {
        const float a = sm[0][t] + sm[1][t] + sm[2][t] + sm[3][t];
        const float b = sq[0][t] + sq[1][t] + sq[2][t] + sq[3][t];
        atomicAdd(&statsCur[t * SSTRIDE], a);
        atomicAdd(&statsCur[1024 + t * SSTRIDE], b);
    }
}

// ---------------- final batchnorm apply ----------------
__global__ __launch_bounds__(256) void k_bn(
    const float* __restrict__ z, const float* __restrict__ stats,
    const float* __restrict__ gamma, const float* __restrict__ beta,
    float* __restrict__ out, int total, float invN)
{
    const int i = blockIdx.x * 256 + threadIdx.x;
    if (i >= total) return;
    const int c = i & 31;
    const float mean = stats[c * SSTRIDE] * invN;
    const float var  = stats[1024 + c * SSTRIDE] * invN - mean * mean;
    out[i] = (z[i] - mean) * rsqrtf(var + EPSV) * gamma[c] + beta[c];
}

extern "C" void kernel_launch(void* const* d_in, const int* in_sizes, int n_in,
                              void* d_out, int out_size, void* d_ws, size_t ws_size,
                              hipStream_t stream) {
    const float* x     = (const float*)d_in[0];
    const int*   ei    = (const int*)  d_in[1];
    const float* Wk    = (const float*)d_in[3];
    const float* bk    = (const float*)d_in[4];
    const float* Wq    = (const float*)d_in[5];
    const float* bq    = (const float*)d_in[6];
    const float* Wv    = (const float*)d_in[7];
    const float* bv    = (const float*)d_in[8];
    const float* Ws    = (const float*)d_in[9];
    const float* bs    = (const float*)d_in[10];
    const float* gamma = (const float*)d_in[11];
    const float* beta  = (const float*)d_in[12];

    const int N = in_sizes[0] / DCH;
    const int E = in_sizes[1] / 2;
    const int NB = (N + BSZ - 1) >> BSH;
    int SGS = 0;
    while (((N - 1) >> SGS) >= NSG) SGS++;   // src group shift
    const int* src = ei;
    const int* dst = ei + E;

    float* ws     = (float*)d_ws;
    float* kbuf   = ws;                                   // N*32 f32 (pre-scaled -log2e*k)
    unsigned short* qvbuf = (unsigned short*)(kbuf + (size_t)N * DCH);   // N*64 u16
    float* zA     = (float*)qvbuf + (size_t)N * DCH;      // N*32 f32
    float* zB     = zA + (size_t)N * DCH;
    float* statsA = zB + (size_t)N * DCH;                 // 2048
    float* statsB = statsA + 2048;                        // 2048
    int*   deg    = (int*)(statsB + 2048);                // N
    int*   off    = deg + N;                              // N
    int*   bcnt   = off + N;                              // NB
    int*   boff   = bcnt + NB;                            // NB+1
    int*   cur    = boff + NB + 1;                        // NB
    unsigned int* pairs = (unsigned int*)(cur + NB);      // E
    int*   ssrc   = (int*)(pairs + E);                    // E

    const int total = N * DCH;
    const float invN = 1.f / (float)N;

    // ---- build src-group-ordered CSR once per launch ----
    hipMemsetAsync(bcnt, 0, (size_t)NB * sizeof(int), stream);
    hipMemsetAsync(cur, 0, (size_t)NB * sizeof(int), stream);
    const int nchunk = (E + CHUNK - 1) / CHUNK;
    k_bucket_hist<<<nchunk, 256, 0, stream>>>(dst, bcnt, E, NB);
    k_scan<<<1, 1024, 0, stream>>>(bcnt, boff, NB);
    k_bucket_scatter<<<nchunk, 256, 0, stream>>>(src, dst, boff, cur, pairs, E, NB);
    k_build_csr2<<<NB, 256, 0, stream>>>(pairs, boff, deg, off, ssrc, N, SGS);

    const float* zprev = x;
    const float* statsPrev = nullptr;
    for (int l = 0; l < 3; ++l) {
        const size_t wo = (size_t)l * DCH * DCH;
        const size_t bo = (size_t)l * DCH;
        float* zcur = (l & 1) ? zB : zA;
        float* statsCur = (l & 1) ? statsB : statsA;
        const float* gPrev = (l > 0) ? gamma + (size_t)(l - 1) * DCH : gamma;
        const float* bPrev = (l > 0) ? beta + (size_t)(l - 1) * DCH : beta;
        const int do_bn = (l > 0) ? 1 : 0;
        const float* sPrev = do_bn ? statsPrev : statsA;

        k_project<<<(N + 7) / 8, 256, 0, stream>>>(
            zprev, sPrev, gPrev, bPrev,
            Wk + wo, bk + bo, Wq + wo, bq + bo, Wv + wo, bv + bo, Ws + wo, bs + bo,
            kbuf, (uint4*)qvbuf, zcur, statsCur, N, do_bn, invN);
        k_edges_csr<<<(N + 31) / 32, 256, 0, stream>>>(
            off, deg, ssrc, (const float4*)kbuf, (const uint4*)qvbuf,
            (const float4*)zprev, sPrev, gPrev, bPrev,
            (float4*)zcur, statsCur, N, (l < 2) ? 1 : 0, do_bn, invN);

        statsPrev = statsCur;
        zprev = zcur;
    }
    k_bn<<<(total + 255) / 256, 256, 0, stream>>>(
        zA, statsA, gamma + 2 * DCH, beta + 2 * DCH, (float*)d_out, total, invN);
}